// Round 6
// baseline (1663.051 us; speedup 1.0000x reference)
//
#include <hip/hip_runtime.h>
#include <math.h>

#define N_NODES  100000
#define N_EDGES  6400000
#define N_GRAPHS 1000
#define D_IN  16
#define D_HID 16
#define D_OUT 6

#define B_NODES   64                                    // nodes per bucket
#define NBUCK     ((N_NODES + B_NODES - 1) / B_NODES)   // 1563
#define CAPB      4608                                  // bucket capacity (mean 4096 + 8 sigma)
#define NSLOTS    ((size_t)NBUCK * CAPB)

// primary (streaming) path
#define EPB_S 8192
#define KB_S  ((N_EDGES + EPB_S - 1) / EPB_S)           // 782

// fallback path (R5)
#define EPB   16384
#define KBLOCKS ((N_EDGES + EPB - 1) / EPB)             // 391

// ===========================================================================
// PRIMARY PATH
// ===========================================================================

// ---------------------------------------------------------------------------
// scatter_stage: one pass over edges. Streams eattr coalescedly and writes
// each edge's 16-float row to a 64B-aligned slot in its dst-bucket slice
// (full-line stores), plus meta = src | (dst&63)<<17. cnt[b] = bucket count.
// ---------------------------------------------------------------------------
__global__ __launch_bounds__(1024) void scatter_stage(
    const int* __restrict__ ei, const float* __restrict__ eattr,
    int* __restrict__ cnt, float* __restrict__ attr64,
    unsigned int* __restrict__ meta)
{
    __shared__ int hist[NBUCK];      // 6.25 KB: counts then rank cursors
    __shared__ int base[NBUCK];      // 6.25 KB: block's reserved base per bucket
    __shared__ int dstbuf[EPB_S];    // 32 KB
    __shared__ int slotbuf[EPB_S];   // 32 KB
    int t = threadIdx.x;
    for (int i = t; i < NBUCK; i += 1024) hist[i] = 0;
    __syncthreads();
    int e0 = blockIdx.x * EPB_S;
    // phase 1: count buckets, cache dst in LDS
#pragma unroll
    for (int k = 0; k < EPB_S / 1024; ++k) {
        int e = e0 + k * 1024 + t;
        int dst = (e < N_EDGES) ? ei[N_EDGES + e] : -1;
        dstbuf[k * 1024 + t] = dst;
        if (dst >= 0) atomicAdd(&hist[dst >> 6], 1);
    }
    __syncthreads();
    // reserve per-bucket ranges globally
    for (int i = t; i < NBUCK; i += 1024) {
        int h = hist[i];
        base[i] = h ? atomicAdd(&cnt[i], h) : 0;
        hist[i] = 0;                 // becomes local rank cursor
    }
    __syncthreads();
    // phase 2: assign slots, write meta
#pragma unroll
    for (int k = 0; k < EPB_S / 1024; ++k) {
        int e = e0 + k * 1024 + t;
        int slot = -1;
        if (e < N_EDGES) {
            int dst = dstbuf[k * 1024 + t];
            int src = ei[e];
            int b = dst >> 6;
            int r = base[b] + atomicAdd(&hist[b], 1);
            if (r < CAPB) {
                slot = b * CAPB + r;
                meta[slot] = (unsigned)src | ((unsigned)(dst & 63) << 17);
            }
        }
        slotbuf[k * 1024 + t] = slot;
    }
    __syncthreads();
    // phase 3: copy attr rows, 16 lanes per edge (coalesced read, full-line write)
    int lane = t & 15, grp = t >> 4;
    int nloc = min(EPB_S, N_EDGES - e0);
    for (int i = grp; i < nloc; i += 64) {
        int slot = slotbuf[i];
        if (slot >= 0) {
            float v = __builtin_nontemporal_load(eattr + (size_t)(e0 + i) * 16 + lane);
            __builtin_nontemporal_store(v, attr64 + (size_t)slot * 16 + lane);
        }
    }
}

// ---------------------------------------------------------------------------
// gather_stream: one block per bucket. Purely linear read of the bucket's
// attr slice + meta; only feat (6.4MB, cache-resident) is random.
// Accumulate relu(attr + feat[src]) into LDS acc[64][16]; coalesced write.
// ---------------------------------------------------------------------------
__global__ __launch_bounds__(1024) void gather_stream(
    const int* __restrict__ cnt, const float* __restrict__ attr64,
    const unsigned int* __restrict__ meta, const float* __restrict__ feat,
    float* __restrict__ aggr)
{
    __shared__ float acc[B_NODES * 16];   // 4 KB
    int t = threadIdx.x;
    int b = blockIdx.x;
    acc[t] = 0.0f;
    __syncthreads();

    int m = cnt[b];
    if (m > CAPB) m = CAPB;
    int lane = t & 15, grp = t >> 4;
    const float* ab = attr64 + (size_t)b * CAPB * 16;
    const unsigned int* mb = meta + (size_t)b * CAPB;

    int i = grp;
    for (; i + 3 * 64 < m; i += 4 * 64) {
        unsigned int md[4];
        float av[4], fv[4];
#pragma unroll
        for (int k = 0; k < 4; ++k) md[k] = mb[i + k * 64];
#pragma unroll
        for (int k = 0; k < 4; ++k)
            av[k] = __builtin_nontemporal_load(ab + (size_t)(i + k * 64) * 16 + lane);
#pragma unroll
        for (int k = 0; k < 4; ++k)
            fv[k] = feat[(size_t)(md[k] & 0x1FFFF) * 16 + lane];
#pragma unroll
        for (int k = 0; k < 4; ++k) {
            int d = (md[k] >> 17) & 63;
            atomicAdd(&acc[d * 16 + lane], fmaxf(av[k] + fv[k], 0.0f));
        }
    }
    for (; i < m; i += 64) {
        unsigned int md = mb[i];
        float v = __builtin_nontemporal_load(ab + (size_t)i * 16 + lane)
                + feat[(size_t)(md & 0x1FFFF) * 16 + lane];
        atomicAdd(&acc[((md >> 17) & 63) * 16 + lane], fmaxf(v, 0.0f));
    }
    __syncthreads();

    int node = b * B_NODES + grp;
    if (node < N_NODES) aggr[(size_t)node * 16 + lane] = acc[t];
}

// ===========================================================================
// FALLBACK PATH (R5, used only if ws_size too small)
// ===========================================================================
__global__ __launch_bounds__(1024) void scatter_direct(
    const int* __restrict__ ei, int* __restrict__ cnt, int2* __restrict__ tmp)
{
    __shared__ int hist[NBUCK];
    __shared__ int base[NBUCK];
    int t = threadIdx.x;
    for (int i = t; i < NBUCK; i += 1024) hist[i] = 0;
    __syncthreads();
    int e0 = blockIdx.x * EPB;
#pragma unroll
    for (int k = 0; k < EPB / 1024; ++k) {
        int e = e0 + k * 1024 + t;
        if (e < N_EDGES) atomicAdd(&hist[ei[N_EDGES + e] >> 6], 1);
    }
    __syncthreads();
    for (int i = t; i < NBUCK; i += 1024) {
        int h = hist[i];
        base[i] = h ? atomicAdd(&cnt[i], h) : 0;
        hist[i] = 0;
    }
    __syncthreads();
#pragma unroll
    for (int k = 0; k < EPB / 1024; ++k) {
        int e = e0 + k * 1024 + t;
        if (e < N_EDGES) {
            int dst = ei[N_EDGES + e];
            int src = ei[e];
            int b = dst >> 6;
            int r = base[b] + atomicAdd(&hist[b], 1);
            if (r < CAPB)
                tmp[(size_t)b * CAPB + r] = make_int2(((dst & 63) << 23) | e, src);
        }
    }
}

__global__ __launch_bounds__(1024) void gather_fused(
    const int* __restrict__ cnt, const int2* __restrict__ tmp,
    const float* __restrict__ feat, const float* __restrict__ eattr,
    float* __restrict__ aggr)
{
    __shared__ float acc[B_NODES * 16];
    int t = threadIdx.x;
    int b = blockIdx.x;
    acc[t] = 0.0f;
    __syncthreads();
    int m = cnt[b];
    if (m > CAPB) m = CAPB;
    const int2* tb = tmp + (size_t)b * CAPB;
    int lane = t & 15, grp = t >> 4;
    for (int i = grp; i < m; i += 64) {
        int2 p = tb[i];
        int   e = p.x & 0x7FFFFF, d = (p.x >> 23) & 63;
        float v = __builtin_nontemporal_load(eattr + (size_t)e * 16 + lane)
                + feat[(size_t)p.y * 16 + lane];
        atomicAdd(&acc[d * 16 + lane], fmaxf(v, 0.0f));
    }
    __syncthreads();
    int node = b * B_NODES + grp;
    if (node < N_NODES) aggr[(size_t)node * 16 + lane] = acc[t];
}

// ===========================================================================
// SHARED: node MLPs, pool
// ===========================================================================
__global__ __launch_bounds__(256) void node1_kernel(
    const float* __restrict__ x, const float* __restrict__ aggr,
    const float* __restrict__ W1a, const float* __restrict__ b1a,
    const float* __restrict__ W1b, const float* __restrict__ b1b,
    float* __restrict__ h)
{
    __shared__ float sWa[256], sWb[256], sba[16], sbb[16];
    int t = threadIdx.x;
    if (t < 256) { sWa[t] = W1a[t]; sWb[t] = W1b[t]; }
    if (t < 16)  { sba[t] = b1a[t]; sbb[t] = b1b[t]; }
    __syncthreads();

    int n = blockIdx.x * blockDim.x + t;
    if (n >= N_NODES) return;

    float v[16];
#pragma unroll
    for (int i = 0; i < 16; ++i) v[i] = x[n * 16 + i] + aggr[n * 16 + i];

    float u[16];
#pragma unroll
    for (int j = 0; j < 16; ++j) {
        float s = sba[j];
#pragma unroll
        for (int i = 0; i < 16; ++i) s += v[i] * sWa[i * 16 + j];
        u[j] = fmaxf(s, 0.0f);
    }
#pragma unroll
    for (int j = 0; j < 16; ++j) {
        float s = sbb[j];
#pragma unroll
        for (int i = 0; i < 16; ++i) s += u[i] * sWb[i * 16 + j];
        h[n * 16 + j] = fmaxf(s, 0.0f);   // outer relu between layers
    }
}

__global__ __launch_bounds__(256) void node2_kernel(
    const float* __restrict__ h, const float* __restrict__ aggr,
    const int* __restrict__ batch,
    const float* __restrict__ W2a, const float* __restrict__ b2a,
    const float* __restrict__ W2b, const float* __restrict__ b2b,
    float* __restrict__ sums, float* __restrict__ counts)
{
    __shared__ float sWa[16 * 6], sWb[6 * 6], sba[6], sbb[6];
    int t = threadIdx.x;
    if (t < 96) sWa[t] = W2a[t];
    if (t < 36) sWb[t] = W2b[t];
    if (t < 6)  { sba[t] = b2a[t]; sbb[t] = b2b[t]; }
    __syncthreads();

    int n = blockIdx.x * blockDim.x + t;
    if (n >= N_NODES) return;

    float v[16];
#pragma unroll
    for (int i = 0; i < 16; ++i) v[i] = h[n * 16 + i] + aggr[n * 16 + i];

    float u[6];
#pragma unroll
    for (int j = 0; j < 6; ++j) {
        float s = sba[j];
#pragma unroll
        for (int i = 0; i < 16; ++i) s += v[i] * sWa[i * 6 + j];
        u[j] = fmaxf(s, 0.0f);
    }
    int g = batch[n];
#pragma unroll
    for (int j = 0; j < 6; ++j) {
        float s = sbb[j];
#pragma unroll
        for (int i = 0; i < 6; ++i) s += u[i] * sWb[i * 6 + j];
        atomicAdd(&sums[g * 6 + j], s);
    }
    atomicAdd(&counts[g], 1.0f);
}

__global__ __launch_bounds__(256) void pool_kernel(
    const float* __restrict__ sums, const float* __restrict__ counts,
    float* __restrict__ out)
{
    int g = blockIdx.x * blockDim.x + threadIdx.x;
    if (g >= N_GRAPHS) return;
    float c = fmaxf(counts[g], 1.0f);
    float p[6];
    float mx = -INFINITY;
#pragma unroll
    for (int j = 0; j < 6; ++j) {
        p[j] = sums[g * 6 + j] / c;
        mx = fmaxf(mx, p[j]);
    }
    float se = 0.0f;
#pragma unroll
    for (int j = 0; j < 6; ++j) se += expf(p[j] - mx);
    float lse = mx + logf(se);
#pragma unroll
    for (int j = 0; j < 6; ++j) out[g * 6 + j] = p[j] - lse;
}

// ---------------------------------------------------------------------------
extern "C" void kernel_launch(void* const* d_in, const int* in_sizes, int n_in,
                              void* d_out, int out_size, void* d_ws, size_t ws_size,
                              hipStream_t stream)
{
    const float* x     = (const float*)d_in[0];
    const int*   ei    = (const int*)  d_in[1];   // [2, E] int32
    const float* eattr = (const float*)d_in[2];
    const int*   batch = (const int*)  d_in[3];
    const float* W1a = (const float*)d_in[4];
    const float* b1a = (const float*)d_in[5];
    const float* W1b = (const float*)d_in[6];
    const float* b1b = (const float*)d_in[7];
    const float* W2a = (const float*)d_in[8];
    const float* b2a = (const float*)d_in[9];
    const float* W2b = (const float*)d_in[10];
    const float* b2b = (const float*)d_in[11];
    float* out = (float*)d_out;

    const int TB = 256;
    const int node_blocks = (N_NODES + TB - 1) / TB;

    // primary-path workspace need: attr64 + meta + aggr + h + cnt + sums + counts
    const size_t need_primary =
        NSLOTS * 16 * sizeof(float) + NSLOTS * sizeof(unsigned int)
        + 2 * (size_t)N_NODES * 16 * sizeof(float)
        + (size_t)NBUCK * sizeof(int)
        + (size_t)(N_GRAPHS * 6 + N_GRAPHS) * sizeof(float) + 4096;

    if (ws_size >= need_primary) {
        // ---- streaming path ----
        float*        attr64 = (float*)d_ws;                        // 460.9 MB
        unsigned int* meta   = (unsigned int*)(attr64 + NSLOTS * 16); // 28.8 MB
        float*        aggr   = (float*)(meta + NSLOTS);             // 6.4 MB
        float*        h      = aggr + (size_t)N_NODES * 16;         // 6.4 MB
        int*          cnt    = (int*)(h + (size_t)N_NODES * 16);
        float*        sums   = (float*)(cnt + NBUCK);
        float*        counts = sums + (size_t)N_GRAPHS * 6;

        hipMemsetAsync(cnt, 0, (size_t)NBUCK * sizeof(int), stream);
        scatter_stage<<<KB_S, 1024, 0, stream>>>(ei, eattr, cnt, attr64, meta);

        gather_stream<<<NBUCK, 1024, 0, stream>>>(cnt, attr64, meta, x, aggr);
        node1_kernel<<<node_blocks, TB, 0, stream>>>(x, aggr, W1a, b1a, W1b, b1b, h);

        gather_stream<<<NBUCK, 1024, 0, stream>>>(cnt, attr64, meta, h, aggr);
        hipMemsetAsync(sums, 0, (size_t)(N_GRAPHS * 6 + N_GRAPHS) * sizeof(float), stream);
        node2_kernel<<<node_blocks, TB, 0, stream>>>(h, aggr, batch, W2a, b2a, W2b, b2b,
                                                     sums, counts);
        pool_kernel<<<(N_GRAPHS + TB - 1) / TB, TB, 0, stream>>>(sums, counts, out);
    } else {
        // ---- fallback path (R5) ----
        int2*  tmp    = (int2*)d_ws;                          // 57.6 MB
        float* aggr   = (float*)(tmp + NSLOTS);               // 6.4 MB
        float* h      = aggr + (size_t)N_NODES * 16;          // 6.4 MB
        int*   cnt    = (int*)(h + (size_t)N_NODES * 16);
        float* sums   = (float*)(cnt + NBUCK);
        float* counts = sums + (size_t)N_GRAPHS * 6;

        hipMemsetAsync(cnt, 0, (size_t)NBUCK * sizeof(int), stream);
        scatter_direct<<<KBLOCKS, 1024, 0, stream>>>(ei, cnt, tmp);

        gather_fused<<<NBUCK, 1024, 0, stream>>>(cnt, tmp, x, eattr, aggr);
        node1_kernel<<<node_blocks, TB, 0, stream>>>(x, aggr, W1a, b1a, W1b, b1b, h);

        gather_fused<<<NBUCK, 1024, 0, stream>>>(cnt, tmp, h, eattr, aggr);
        hipMemsetAsync(sums, 0, (size_t)(N_GRAPHS * 6 + N_GRAPHS) * sizeof(float), stream);
        node2_kernel<<<node_blocks, TB, 0, stream>>>(h, aggr, batch, W2a, b2a, W2b, b2b,
                                                     sums, counts);
        pool_kernel<<<(N_GRAPHS + TB - 1) / TB, TB, 0, stream>>>(sums, counts, out);
    }
}

// Round 7
// 1393.370 us; speedup vs baseline: 1.1935x; 1.1935x over previous
//
#include <hip/hip_runtime.h>
#include <math.h>

#define N_NODES  100000
#define N_EDGES  6400000
#define N_GRAPHS 1000
#define D_IN  16
#define D_HID 16
#define D_OUT 6

#define B_NODES   64                                    // nodes per bucket
#define NBUCK     ((N_NODES + B_NODES - 1) / B_NODES)   // 1563
#define CAPB      4608                                  // bucket capacity (mean 4096 + 8 sigma)
#define EPB       16384                                 // edges per scatter block
#define KBLOCKS   ((N_EDGES + EPB - 1) / EPB)           // 391

// ---------------------------------------------------------------------------
// K1: single-pass bucket scatter (R5, proven ~120us). Per-block LDS histogram
// -> one global atomic reservation per (block,bucket) -> scatter
// {(dstLow<<23)|e, src} into the bucket's fixed-capacity slice.
// cnt[b] ends as the bucket's edge count.
// ---------------------------------------------------------------------------
__global__ __launch_bounds__(1024) void scatter_direct(
    const int* __restrict__ ei, int* __restrict__ cnt, int2* __restrict__ tmp)
{
    __shared__ int hist[NBUCK];
    __shared__ int base[NBUCK];
    int t = threadIdx.x;
    for (int i = t; i < NBUCK; i += 1024) hist[i] = 0;
    __syncthreads();
    int e0 = blockIdx.x * EPB;
#pragma unroll
    for (int k = 0; k < EPB / 1024; ++k) {
        int e = e0 + k * 1024 + t;
        if (e < N_EDGES) atomicAdd(&hist[ei[N_EDGES + e] >> 6], 1);
    }
    __syncthreads();
    for (int i = t; i < NBUCK; i += 1024) {
        int h = hist[i];
        base[i] = h ? atomicAdd(&cnt[i], h) : 0;
        hist[i] = 0;              // becomes local rank cursor
    }
    __syncthreads();
#pragma unroll
    for (int k = 0; k < EPB / 1024; ++k) {
        int e = e0 + k * 1024 + t;
        if (e < N_EDGES) {
            int dst = ei[N_EDGES + e];
            int src = ei[e];
            int b = dst >> 6;
            int r = base[b] + atomicAdd(&hist[b], 1);
            if (r < CAPB)         // safety (statistically never)
                tmp[(size_t)b * CAPB + r] = make_int2(((dst & 63) << 23) | e, src);
        }
    }
}

// ---------------------------------------------------------------------------
// K2: per-bucket gather, 256 threads, NO launch bounds (VGPR headroom),
// explicit 3-phase 8-deep body: 8 tmp loads -> 8 eattr + 8 feat loads ->
// 8 LDS ds_add_f32. 16 lanes per edge (lane = channel).
// ---------------------------------------------------------------------------
__global__ void gather_fused(
    const int* __restrict__ cnt, const int2* __restrict__ tmp,
    const float* __restrict__ feat, const float* __restrict__ eattr,
    float* __restrict__ aggr)
{
    __shared__ float acc[B_NODES * 16];   // 4 KB
    int t = threadIdx.x;                  // 256
    int b = blockIdx.x;
    for (int i = t; i < B_NODES * 16; i += 256) acc[i] = 0.0f;
    __syncthreads();

    int m = cnt[b];
    if (m > CAPB) m = CAPB;
    const int2* tb = tmp + (size_t)b * CAPB;
    int lane = t & 15, grp = t >> 4;      // 16 edge-groups per block

    int i = grp;
    for (; i + 7 * 16 < m; i += 8 * 16) {
        int2 p[8];
#pragma unroll
        for (int k = 0; k < 8; ++k) p[k] = tb[i + k * 16];
        float ev[8];
#pragma unroll
        for (int k = 0; k < 8; ++k)
            ev[k] = __builtin_nontemporal_load(
                        eattr + (size_t)(p[k].x & 0x7FFFFF) * 16 + lane);
        float fv[8];
#pragma unroll
        for (int k = 0; k < 8; ++k)
            fv[k] = feat[(size_t)p[k].y * 16 + lane];
#pragma unroll
        for (int k = 0; k < 8; ++k)
            atomicAdd(&acc[((p[k].x >> 23) & 63) * 16 + lane],
                      fmaxf(ev[k] + fv[k], 0.0f));
    }
    for (; i < m; i += 16) {
        int2 p = tb[i];
        float v = __builtin_nontemporal_load(
                      eattr + (size_t)(p.x & 0x7FFFFF) * 16 + lane)
                + feat[(size_t)p.y * 16 + lane];
        atomicAdd(&acc[((p.x >> 23) & 63) * 16 + lane], fmaxf(v, 0.0f));
    }
    __syncthreads();

    // coalesced 4KB write: acc[j] -> aggr[b*1024 + j]
    for (int j = t; j < B_NODES * 16; j += 256) {
        int node = b * B_NODES + (j >> 4);
        if (node < N_NODES) aggr[(size_t)node * 16 + (j & 15)] = acc[j];
    }
}

// ---------------------------------------------------------------------------
// Node MLP layer 1: h = relu( relu((x+aggr)@W1a + b1a) @ W1b + b1b )
// ---------------------------------------------------------------------------
__global__ __launch_bounds__(256) void node1_kernel(
    const float* __restrict__ x, const float* __restrict__ aggr,
    const float* __restrict__ W1a, const float* __restrict__ b1a,
    const float* __restrict__ W1b, const float* __restrict__ b1b,
    float* __restrict__ h)
{
    __shared__ float sWa[256], sWb[256], sba[16], sbb[16];
    int t = threadIdx.x;
    if (t < 256) { sWa[t] = W1a[t]; sWb[t] = W1b[t]; }
    if (t < 16)  { sba[t] = b1a[t]; sbb[t] = b1b[t]; }
    __syncthreads();

    int n = blockIdx.x * blockDim.x + t;
    if (n >= N_NODES) return;

    float v[16];
#pragma unroll
    for (int i = 0; i < 16; ++i) v[i] = x[n * 16 + i] + aggr[n * 16 + i];

    float u[16];
#pragma unroll
    for (int j = 0; j < 16; ++j) {
        float s = sba[j];
#pragma unroll
        for (int i = 0; i < 16; ++i) s += v[i] * sWa[i * 16 + j];
        u[j] = fmaxf(s, 0.0f);
    }
#pragma unroll
    for (int j = 0; j < 16; ++j) {
        float s = sbb[j];
#pragma unroll
        for (int i = 0; i < 16; ++i) s += u[i] * sWb[i * 16 + j];
        h[n * 16 + j] = fmaxf(s, 0.0f);   // outer relu between layers
    }
}

// ---------------------------------------------------------------------------
// Node MLP layer 2 + pooling accumulation
// ---------------------------------------------------------------------------
__global__ __launch_bounds__(256) void node2_kernel(
    const float* __restrict__ h, const float* __restrict__ aggr,
    const int* __restrict__ batch,
    const float* __restrict__ W2a, const float* __restrict__ b2a,
    const float* __restrict__ W2b, const float* __restrict__ b2b,
    float* __restrict__ sums, float* __restrict__ counts)
{
    __shared__ float sWa[16 * 6], sWb[6 * 6], sba[6], sbb[6];
    int t = threadIdx.x;
    if (t < 96) sWa[t] = W2a[t];
    if (t < 36) sWb[t] = W2b[t];
    if (t < 6)  { sba[t] = b2a[t]; sbb[t] = b2b[t]; }
    __syncthreads();

    int n = blockIdx.x * blockDim.x + t;
    if (n >= N_NODES) return;

    float v[16];
#pragma unroll
    for (int i = 0; i < 16; ++i) v[i] = h[n * 16 + i] + aggr[n * 16 + i];

    float u[6];
#pragma unroll
    for (int j = 0; j < 6; ++j) {
        float s = sba[j];
#pragma unroll
        for (int i = 0; i < 16; ++i) s += v[i] * sWa[i * 6 + j];
        u[j] = fmaxf(s, 0.0f);
    }
    int g = batch[n];
#pragma unroll
    for (int j = 0; j < 6; ++j) {
        float s = sbb[j];
#pragma unroll
        for (int i = 0; i < 6; ++i) s += u[i] * sWb[i * 6 + j];
        atomicAdd(&sums[g * 6 + j], s);
    }
    atomicAdd(&counts[g], 1.0f);
}

// ---------------------------------------------------------------------------
// Pool + log_softmax
// ---------------------------------------------------------------------------
__global__ __launch_bounds__(256) void pool_kernel(
    const float* __restrict__ sums, const float* __restrict__ counts,
    float* __restrict__ out)
{
    int g = blockIdx.x * blockDim.x + threadIdx.x;
    if (g >= N_GRAPHS) return;
    float c = fmaxf(counts[g], 1.0f);
    float p[6];
    float mx = -INFINITY;
#pragma unroll
    for (int j = 0; j < 6; ++j) {
        p[j] = sums[g * 6 + j] / c;
        mx = fmaxf(mx, p[j]);
    }
    float se = 0.0f;
#pragma unroll
    for (int j = 0; j < 6; ++j) se += expf(p[j] - mx);
    float lse = mx + logf(se);
#pragma unroll
    for (int j = 0; j < 6; ++j) out[g * 6 + j] = p[j] - lse;
}

// ---------------------------------------------------------------------------
extern "C" void kernel_launch(void* const* d_in, const int* in_sizes, int n_in,
                              void* d_out, int out_size, void* d_ws, size_t ws_size,
                              hipStream_t stream)
{
    const float* x     = (const float*)d_in[0];
    const int*   ei    = (const int*)  d_in[1];   // [2, E] int32
    const float* eattr = (const float*)d_in[2];
    const int*   batch = (const int*)  d_in[3];
    const float* W1a = (const float*)d_in[4];
    const float* b1a = (const float*)d_in[5];
    const float* W1b = (const float*)d_in[6];
    const float* b1b = (const float*)d_in[7];
    const float* W2a = (const float*)d_in[8];
    const float* b2a = (const float*)d_in[9];
    const float* W2b = (const float*)d_in[10];
    const float* b2b = (const float*)d_in[11];
    float* out = (float*)d_out;

    // ---- workspace layout (~71 MB) ----
    int2*  tmp    = (int2*)d_ws;                          // [NBUCK*CAPB]  57.6 MB
    float* aggr   = (float*)(tmp + (size_t)NBUCK * CAPB); // [N,16]         6.4 MB
    float* h      = aggr + (size_t)N_NODES * 16;          // [N,16]         6.4 MB
    int*   cnt    = (int*)(h + (size_t)N_NODES * 16);     // [NBUCK]
    float* sums   = (float*)(cnt + NBUCK);                // [G,6]
    float* counts = sums + (size_t)N_GRAPHS * 6;          // [G]

    const int TB = 256;
    const int node_blocks = (N_NODES + TB - 1) / TB;

    // ---- bucket scatter (shared by both layers) ----
    hipMemsetAsync(cnt, 0, (size_t)NBUCK * sizeof(int), stream);
    scatter_direct<<<KBLOCKS, 1024, 0, stream>>>(ei, cnt, tmp);

    // ---- layer 1 ----
    gather_fused<<<NBUCK, TB, 0, stream>>>(cnt, tmp, x, eattr, aggr);
    node1_kernel<<<node_blocks, TB, 0, stream>>>(x, aggr, W1a, b1a, W1b, b1b, h);

    // ---- layer 2 ----
    gather_fused<<<NBUCK, TB, 0, stream>>>(cnt, tmp, h, eattr, aggr);
    hipMemsetAsync(sums, 0, (size_t)(N_GRAPHS * 6 + N_GRAPHS) * sizeof(float), stream);
    node2_kernel<<<node_blocks, TB, 0, stream>>>(h, aggr, batch, W2a, b2a, W2b, b2b,
                                                 sums, counts);

    // ---- pool + log_softmax ----
    pool_kernel<<<(N_GRAPHS + TB - 1) / TB, TB, 0, stream>>>(sums, counts, out);
}

// Round 8
// 639.008 us; speedup vs baseline: 2.6026x; 2.1805x over previous
//
#include <hip/hip_runtime.h>
#include <math.h>

#define N_NODES  100000
#define N_EDGES  6400000
#define N_GRAPHS 1000
#define D_IN  16
#define D_HID 16
#define D_OUT 6

#define B_NODES   64                                    // nodes per bucket
#define NBUCK     ((N_NODES + B_NODES - 1) / B_NODES)   // 1563
#define CAPB      4608                                  // bucket capacity (mean 4096 + 8 sigma)
#define NSLOTS    ((size_t)NBUCK * CAPB)
#define EPB       16384                                 // edges per scatter block
#define KBLOCKS   ((N_EDGES + EPB - 1) / EPB)           // 391

// ---------------------------------------------------------------------------
// K1: single-pass bucket scatter. Per-block LDS histogram -> one global
// atomic reservation per (block,bucket) -> scatter {(dstLow<<23)|e, src}
// into the bucket's fixed slice tmp[b*CAPB..]. cnt[b] = bucket edge count.
// ---------------------------------------------------------------------------
__global__ __launch_bounds__(1024) void scatter_direct(
    const int* __restrict__ ei, int* __restrict__ cnt, int2* __restrict__ tmp)
{
    __shared__ int hist[NBUCK];
    __shared__ int base[NBUCK];
    int t = threadIdx.x;
    for (int i = t; i < NBUCK; i += 1024) hist[i] = 0;
    __syncthreads();
    int e0 = blockIdx.x * EPB;
#pragma unroll
    for (int k = 0; k < EPB / 1024; ++k) {
        int e = e0 + k * 1024 + t;
        if (e < N_EDGES) atomicAdd(&hist[ei[N_EDGES + e] >> 6], 1);
    }
    __syncthreads();
    for (int i = t; i < NBUCK; i += 1024) {
        int h = hist[i];
        base[i] = h ? atomicAdd(&cnt[i], h) : 0;
        hist[i] = 0;              // becomes local rank cursor
    }
    __syncthreads();
#pragma unroll
    for (int k = 0; k < EPB / 1024; ++k) {
        int e = e0 + k * 1024 + t;
        if (e < N_EDGES) {
            int dst = ei[N_EDGES + e];
            int src = ei[e];
            int b = dst >> 6;
            int r = base[b] + atomicAdd(&hist[b], 1);
            if (r < CAPB)         // safety (statistically never)
                tmp[(size_t)b * CAPB + r] = make_int2(((dst & 63) << 23) | e, src);
        }
    }
}

// ---------------------------------------------------------------------------
// K2: per-bucket counting sort in LDS -> node-major CSR {src,e} within the
// bucket slice + per-node (beg,end). Proven-cheap in R3 (<~60us).
// ---------------------------------------------------------------------------
__global__ __launch_bounds__(1024) void bucket_place(
    const int* __restrict__ cnt, const int2* __restrict__ tmp,
    int2* __restrict__ csr, int2* __restrict__ offs2)
{
    __shared__ int2 stage[CAPB];      // 36.9 KB
    __shared__ int hist[B_NODES];
    int b = blockIdx.x, t = threadIdx.x;
    int m = cnt[b];
    if (m > CAPB) m = CAPB;
    int beg = b * CAPB;
    for (int i = t; i < m; i += 1024) stage[i] = tmp[beg + i];
    if (t < B_NODES) hist[t] = 0;
    __syncthreads();
    for (int i = t; i < m; i += 1024)
        atomicAdd(&hist[(stage[i].x >> 23) & 63], 1);
    __syncthreads();
    if (t < 64) {
        int v = hist[t], sc = v;
#pragma unroll
        for (int d = 1; d < 64; d <<= 1) {
            int o = __shfl_up(sc, d, 64);
            if (t >= d) sc += o;
        }
        int ex = sc - v;
        int node = b * 64 + t;
        if (node < N_NODES) offs2[node] = make_int2(beg + ex, beg + ex + v);
        hist[t] = ex;                 // becomes scatter cursor
    }
    __syncthreads();
    for (int i = t; i < m; i += 1024) {
        int2 p = stage[i];
        int d = (p.x >> 23) & 63;
        int e = p.x & 0x7FFFFF;
        int r = atomicAdd(&hist[d], 1);
        csr[beg + r] = make_int2(p.y, e);   // {src, e}
    }
}

// ---------------------------------------------------------------------------
// K3: per-node gather, REGISTER accumulation (no LDS ops in the hot loop ->
// compiler can software-pipeline loads across iterations; R3 proved ~4 TB/s).
// 16 lanes per node (lane = channel), 16 nodes per 256-thread block, 8-deep.
// ---------------------------------------------------------------------------
__global__ __launch_bounds__(256) void gather_csr(
    const int2* __restrict__ offs2, const int2* __restrict__ csr,
    const float* __restrict__ feat, const float* __restrict__ eattr,
    float* __restrict__ aggr)
{
    int t = threadIdx.x;
    int lane = t & 15, grp = t >> 4;
    int n = blockIdx.x * 16 + grp;
    if (n >= N_NODES) return;
    int2 oo = offs2[n];
    int i = oo.x, end = oo.y;
    float acc = 0.0f;
    for (; i + 8 <= end; i += 8) {
        int2 p[8];
#pragma unroll
        for (int k = 0; k < 8; ++k) p[k] = csr[i + k];
        float ev[8];
#pragma unroll
        for (int k = 0; k < 8; ++k)
            ev[k] = __builtin_nontemporal_load(eattr + (size_t)p[k].y * 16 + lane);
        float fv[8];
#pragma unroll
        for (int k = 0; k < 8; ++k)
            fv[k] = feat[(size_t)p[k].x * 16 + lane];
#pragma unroll
        for (int k = 0; k < 8; ++k)
            acc += fmaxf(ev[k] + fv[k], 0.0f);
    }
    for (; i < end; ++i) {
        int2 p = csr[i];
        acc += fmaxf(__builtin_nontemporal_load(eattr + (size_t)p.y * 16 + lane)
                     + feat[(size_t)p.x * 16 + lane], 0.0f);
    }
    aggr[(size_t)n * 16 + lane] = acc;
}

// ---------------------------------------------------------------------------
// Node MLP layer 1: h = relu( relu((x+aggr)@W1a + b1a) @ W1b + b1b )
// ---------------------------------------------------------------------------
__global__ __launch_bounds__(256) void node1_kernel(
    const float* __restrict__ x, const float* __restrict__ aggr,
    const float* __restrict__ W1a, const float* __restrict__ b1a,
    const float* __restrict__ W1b, const float* __restrict__ b1b,
    float* __restrict__ h)
{
    __shared__ float sWa[256], sWb[256], sba[16], sbb[16];
    int t = threadIdx.x;
    if (t < 256) { sWa[t] = W1a[t]; sWb[t] = W1b[t]; }
    if (t < 16)  { sba[t] = b1a[t]; sbb[t] = b1b[t]; }
    __syncthreads();

    int n = blockIdx.x * blockDim.x + t;
    if (n >= N_NODES) return;

    float v[16];
#pragma unroll
    for (int i = 0; i < 16; ++i) v[i] = x[n * 16 + i] + aggr[n * 16 + i];

    float u[16];
#pragma unroll
    for (int j = 0; j < 16; ++j) {
        float s = sba[j];
#pragma unroll
        for (int i = 0; i < 16; ++i) s += v[i] * sWa[i * 16 + j];
        u[j] = fmaxf(s, 0.0f);
    }
#pragma unroll
    for (int j = 0; j < 16; ++j) {
        float s = sbb[j];
#pragma unroll
        for (int i = 0; i < 16; ++i) s += u[i] * sWb[i * 16 + j];
        h[n * 16 + j] = fmaxf(s, 0.0f);   // outer relu between layers
    }
}

// ---------------------------------------------------------------------------
// Node MLP layer 2 + pooling accumulation
// ---------------------------------------------------------------------------
__global__ __launch_bounds__(256) void node2_kernel(
    const float* __restrict__ h, const float* __restrict__ aggr,
    const int* __restrict__ batch,
    const float* __restrict__ W2a, const float* __restrict__ b2a,
    const float* __restrict__ W2b, const float* __restrict__ b2b,
    float* __restrict__ sums, float* __restrict__ counts)
{
    __shared__ float sWa[16 * 6], sWb[6 * 6], sba[6], sbb[6];
    int t = threadIdx.x;
    if (t < 96) sWa[t] = W2a[t];
    if (t < 36) sWb[t] = W2b[t];
    if (t < 6)  { sba[t] = b2a[t]; sbb[t] = b2b[t]; }
    __syncthreads();

    int n = blockIdx.x * blockDim.x + t;
    if (n >= N_NODES) return;

    float v[16];
#pragma unroll
    for (int i = 0; i < 16; ++i) v[i] = h[n * 16 + i] + aggr[n * 16 + i];

    float u[6];
#pragma unroll
    for (int j = 0; j < 6; ++j) {
        float s = sba[j];
#pragma unroll
        for (int i = 0; i < 16; ++i) s += v[i] * sWa[i * 6 + j];
        u[j] = fmaxf(s, 0.0f);
    }
    int g = batch[n];
#pragma unroll
    for (int j = 0; j < 6; ++j) {
        float s = sbb[j];
#pragma unroll
        for (int i = 0; i < 6; ++i) s += u[i] * sWb[i * 6 + j];
        atomicAdd(&sums[g * 6 + j], s);
    }
    atomicAdd(&counts[g], 1.0f);
}

// ---------------------------------------------------------------------------
// Pool + log_softmax
// ---------------------------------------------------------------------------
__global__ __launch_bounds__(256) void pool_kernel(
    const float* __restrict__ sums, const float* __restrict__ counts,
    float* __restrict__ out)
{
    int g = blockIdx.x * blockDim.x + threadIdx.x;
    if (g >= N_GRAPHS) return;
    float c = fmaxf(counts[g], 1.0f);
    float p[6];
    float mx = -INFINITY;
#pragma unroll
    for (int j = 0; j < 6; ++j) {
        p[j] = sums[g * 6 + j] / c;
        mx = fmaxf(mx, p[j]);
    }
    float se = 0.0f;
#pragma unroll
    for (int j = 0; j < 6; ++j) se += expf(p[j] - mx);
    float lse = mx + logf(se);
#pragma unroll
    for (int j = 0; j < 6; ++j) out[g * 6 + j] = p[j] - lse;
}

// ---------------------------------------------------------------------------
extern "C" void kernel_launch(void* const* d_in, const int* in_sizes, int n_in,
                              void* d_out, int out_size, void* d_ws, size_t ws_size,
                              hipStream_t stream)
{
    const float* x     = (const float*)d_in[0];
    const int*   ei    = (const int*)  d_in[1];   // [2, E] int32
    const float* eattr = (const float*)d_in[2];
    const int*   batch = (const int*)  d_in[3];
    const float* W1a = (const float*)d_in[4];
    const float* b1a = (const float*)d_in[5];
    const float* W1b = (const float*)d_in[6];
    const float* b1b = (const float*)d_in[7];
    const float* W2a = (const float*)d_in[8];
    const float* b2a = (const float*)d_in[9];
    const float* W2b = (const float*)d_in[10];
    const float* b2b = (const float*)d_in[11];
    float* out = (float*)d_out;

    // ---- workspace layout (~130 MB) ----
    int2*  tmp    = (int2*)d_ws;                          // [NSLOTS]  57.6 MB
    int2*  csr    = tmp + NSLOTS;                         // [NSLOTS]  57.6 MB
    float* aggr   = (float*)(csr + NSLOTS);               // [N,16]     6.4 MB
    float* h      = aggr + (size_t)N_NODES * 16;          // [N,16]     6.4 MB
    int2*  offs2  = (int2*)(h + (size_t)N_NODES * 16);    // [N]        0.8 MB
    int*   cnt    = (int*)(offs2 + N_NODES);              // [NBUCK]
    float* sums   = (float*)(cnt + NBUCK);                // [G,6]
    float* counts = sums + (size_t)N_GRAPHS * 6;          // [G]

    const int TB = 256;
    const int node_blocks = (N_NODES + TB - 1) / TB;
    const int gather_blocks = (N_NODES + 15) / 16;        // 6250

    // ---- CSR build: bucket scatter + per-bucket counting sort ----
    hipMemsetAsync(cnt, 0, (size_t)NBUCK * sizeof(int), stream);
    scatter_direct<<<KBLOCKS, 1024, 0, stream>>>(ei, cnt, tmp);
    bucket_place<<<NBUCK, 1024, 0, stream>>>(cnt, tmp, csr, offs2);

    // ---- layer 1 ----
    gather_csr<<<gather_blocks, TB, 0, stream>>>(offs2, csr, x, eattr, aggr);
    node1_kernel<<<node_blocks, TB, 0, stream>>>(x, aggr, W1a, b1a, W1b, b1b, h);

    // ---- layer 2 ----
    gather_csr<<<gather_blocks, TB, 0, stream>>>(offs2, csr, h, eattr, aggr);
    hipMemsetAsync(sums, 0, (size_t)(N_GRAPHS * 6 + N_GRAPHS) * sizeof(float), stream);
    node2_kernel<<<node_blocks, TB, 0, stream>>>(h, aggr, batch, W2a, b2a, W2b, b2b,
                                                 sums, counts);

    // ---- pool + log_softmax ----
    pool_kernel<<<(N_GRAPHS + TB - 1) / TB, TB, 0, stream>>>(sums, counts, out);
}